// Round 8
// baseline (159.930 us; speedup 1.0000x reference)
//
#include <hip/hip_runtime.h>
#include <hip/hip_bf16.h>
#include <math.h>

#define BATCH 4096
#define XD    784
#define HDIM  512
#define ZD    16
#define NS    8
#define ZS    128
#define NSAMP (BATCH * NS)   // 32768
#define STDN  (ZD * NS * NS) // 1024
#define KP1   800            // K of enc1, padded 784->800
#define NMS   1152           // 128 (mu) + 1024 (std1)
#define NP2   800            // w2t rows padded 784->800 (5*160)

typedef __attribute__((ext_vector_type(8))) short bf16x8;
typedef __attribute__((ext_vector_type(4))) float f32x4;

__device__ inline unsigned short f2bf(float f) {
    unsigned int u = __float_as_uint(f);
    unsigned int r = (u + 0x7fffu + ((u >> 16) & 1u)) >> 16;
    return (unsigned short)r;
}

// HBM -> LDS direct 16B async copy (global_load_lds_dwordx4).
__device__ __forceinline__ void gload16(const unsigned short* g, unsigned short* l) {
    __builtin_amdgcn_global_load_lds(
        (const __attribute__((address_space(1))) unsigned int*)g,
        (__attribute__((address_space(3))) unsigned int*)l,
        16, 0, 0);
}

// ---------------------------------------------------------------------------
// Merged prep (unchanged from R7): block ranges
//   [0,1600)    : W1^T   -> w1t [512][800]
//   [1600,3200) : xpad   -> x_bf [4096][800]
//   [3200,5504) : [Wmu|Wstd]^T -> wmst [1152][512]
//   [5504,7104) : Wd2^T  -> w2tp [800][512] (rows>=784 zero)
// ---------------------------------------------------------------------------
__global__ __launch_bounds__(256)
void prep_kernel(const float* __restrict__ W1, const float* __restrict__ x,
                 const float* __restrict__ Wmu, const float* __restrict__ Wstd,
                 const float* __restrict__ Wd2,
                 unsigned short* __restrict__ w1t, unsigned short* __restrict__ x_bf,
                 unsigned short* __restrict__ wmst, unsigned short* __restrict__ w2tp)
{
    __shared__ unsigned short t[16][17];
    const int tid = threadIdx.x;
    const int tx = tid & 15, ty = tid >> 4;
    const int bid = blockIdx.x;

    if (bid < 1600) {                      // W1^T (K=784 -> 800, N=512)
        const int bx = bid & 31, by = bid >> 5;        // 32 x 50
        const int n = bx * 16 + tx, k = by * 16 + ty;
        t[ty][tx] = (k < XD) ? f2bf(W1[(size_t)k * HDIM + n]) : (unsigned short)0;
        __syncthreads();
        w1t[(size_t)(bx * 16 + ty) * KP1 + (by * 16 + tx)] = t[tx][ty];
    } else if (bid < 3200) {               // xpad
        const int idx = (bid - 1600) * 256 + tid;
        const int row = idx / 100;
        const int c8 = idx - row * 100;
        const int k0 = c8 * 8;
        ushort4 o0 = {0, 0, 0, 0}, o1 = {0, 0, 0, 0};
        if (k0 < XD) {
            const float4 a = *reinterpret_cast<const float4*>(&x[(size_t)row * XD + k0]);
            const float4 b = *reinterpret_cast<const float4*>(&x[(size_t)row * XD + k0 + 4]);
            o0.x = f2bf(a.x); o0.y = f2bf(a.y); o0.z = f2bf(a.z); o0.w = f2bf(a.w);
            o1.x = f2bf(b.x); o1.y = f2bf(b.y); o1.z = f2bf(b.z); o1.w = f2bf(b.w);
        }
        *reinterpret_cast<ushort4*>(&x_bf[(size_t)row * KP1 + k0]) = o0;
        *reinterpret_cast<ushort4*>(&x_bf[(size_t)row * KP1 + k0 + 4]) = o1;
    } else if (bid < 5504) {               // [Wmu|Wstd]^T (N=1152, K=512)
        const int b = bid - 3200;                      // 72 x 32
        const int bx = b % 72, by = b / 72;
        const int n = bx * 16 + tx, k = by * 16 + ty;
        const float v = (n < ZS) ? Wmu[(size_t)k * ZS + n]
                                 : Wstd[(size_t)k * STDN + (n - ZS)];
        t[ty][tx] = f2bf(v);
        __syncthreads();
        wmst[(size_t)(bx * 16 + ty) * HDIM + (by * 16 + tx)] = t[tx][ty];
    } else {                               // Wd2^T (N=784 -> 800 rows, K=512)
        const int b = bid - 5504;                      // 50 x 32
        const int bx = b % 50, by = b / 50;
        const int n = bx * 16 + tx, k = by * 16 + ty;
        t[ty][tx] = (n < XD) ? f2bf(Wd2[(size_t)k * XD + n]) : (unsigned short)0;
        __syncthreads();
        w2tp[(size_t)(bx * 16 + ty) * HDIM + (by * 16 + tx)] = t[tx][ty];
    }
}

// ---------------------------------------------------------------------------
// Encoder MFMA GEMM (unchanged from R7, known-good).
// ---------------------------------------------------------------------------
template<int OUT_BF16>
__global__ __launch_bounds__(256)
void enc_mfma(const unsigned short* __restrict__ A,
              const unsigned short* __restrict__ Bt,
              const float* __restrict__ bias0, const float* __restrict__ bias1,
              int bsplit, void* __restrict__ Cout, int ldc, int K)
{
    __shared__ __align__(16) unsigned short Al[2][128 * 32];
    __shared__ __align__(16) unsigned short Bl[2][128 * 32];

    const int tid = threadIdx.x;
    const int m0 = blockIdx.x * 128;
    const int n0 = blockIdx.y * 128;
    const int wave = tid >> 6;
    const int lane = tid & 63;
    const int lr = lane & 15;
    const int kg = lane >> 4;
    const int nkt = K >> 5;

    const int rS = tid >> 2;
    const int cS = (tid & 3) * 8;

    f32x4 acc[2][8];
    #pragma unroll
    for (int i = 0; i < 2; ++i)
        #pragma unroll
        for (int j = 0; j < 8; ++j)
            acc[i][j] = (f32x4){0.f, 0.f, 0.f, 0.f};

    #define ENC_STAGE(b, kt)                                                          \
    {                                                                                 \
        const int k0 = (kt) * 32 + cS;                                                \
        gload16(&A[(size_t)(m0 + rS) * K + k0],       &Al[b][(size_t)tid * 8]);       \
        gload16(&A[(size_t)(m0 + rS + 64) * K + k0],  &Al[b][(size_t)(tid + 256) * 8]);\
        gload16(&Bt[(size_t)(n0 + rS) * K + k0],      &Bl[b][(size_t)tid * 8]);       \
        gload16(&Bt[(size_t)(n0 + rS + 64) * K + k0], &Bl[b][(size_t)(tid + 256) * 8]);\
    }

    ENC_STAGE(0, 0);
    __syncthreads();

    int buf = 0;
    for (int kt = 0; kt < nkt; ++kt) {
        if (kt + 1 < nkt) ENC_STAGE(buf ^ 1, kt + 1);

        bf16x8 af[2], bfr[8];
        #pragma unroll
        for (int mi = 0; mi < 2; ++mi)
            af[mi] = *reinterpret_cast<const bf16x8*>(
                &Al[buf][(wave * 32 + mi * 16 + lr) * 32 + kg * 8]);
        #pragma unroll
        for (int nf = 0; nf < 8; ++nf)
            bfr[nf] = *reinterpret_cast<const bf16x8*>(
                &Bl[buf][(nf * 16 + lr) * 32 + kg * 8]);
        #pragma unroll
        for (int mi = 0; mi < 2; ++mi)
            #pragma unroll
            for (int nf = 0; nf < 8; ++nf)
                acc[mi][nf] = __builtin_amdgcn_mfma_f32_16x16x32_bf16(af[mi], bfr[nf], acc[mi][nf], 0, 0, 0);

        __syncthreads();
        buf ^= 1;
    }

    const int mrow = m0 + wave * 32;
    #pragma unroll
    for (int nf = 0; nf < 8; ++nf) {
        const int col = n0 + nf * 16 + lr;
        const float bb = (col < bsplit) ? bias0[col] : bias1[col - bsplit];
        #pragma unroll
        for (int mi = 0; mi < 2; ++mi) {
            #pragma unroll
            for (int j = 0; j < 4; ++j) {
                const int row = mrow + mi * 16 + kg * 4 + j;
                const float v = acc[mi][nf][j] + bb;
                if (OUT_BF16)
                    ((unsigned short*)Cout)[(size_t)row * ldc + col] = f2bf(fmaxf(v, 0.f));
                else
                    ((float*)Cout)[(size_t)row * ldc + col] = v;
            }
        }
    }
    #undef ENC_STAGE
}

// ---------------------------------------------------------------------------
// Sparse sample (unchanged).
// ---------------------------------------------------------------------------
__global__ __launch_bounds__(256)
void sample_kernel(const float* __restrict__ ms, const float* __restrict__ eps,
                   float* __restrict__ mu_out,
                   float* __restrict__ z_out, float* __restrict__ logvar_out)
{
    const int idx = blockIdx.x * 256 + threadIdx.x;
    const int b = idx >> 7;
    const int r = idx & 127;
    const int d = r & 15;
    const int s1 = r >> 4;

    const float* v = &ms[(size_t)b * NMS + ZS + r * NS];
    const float* e = &eps[(size_t)b * ZS + d];
    float zacc = 0.f, dacc = 0.f;
    #pragma unroll
    for (int k = 0; k < NS; ++k) {
        const float vv = v[k];
        zacc += vv * e[16 * k];
        dacc += vv * vv;
    }
    const float muv = ms[(size_t)b * NMS + r];
    mu_out[(size_t)b * ZS + r] = muv;
    const float zv = muv + zacc;
    const size_t orow = (size_t)(b * NS + s1) * ZD + d;
    z_out[orow] = zv;
    logvar_out[orow] = logf(dacc);
}

// ---------------------------------------------------------------------------
// hd = relu(z @ Wd1 + bd1) in bf16 (unchanged).
// ---------------------------------------------------------------------------
__global__ __launch_bounds__(256)
void hd_kernel(const float* __restrict__ z, const float* __restrict__ Wd1,
               const float* __restrict__ bd1, unsigned short* __restrict__ hd)
{
    const int idx = blockIdx.x * 256 + threadIdx.x;
    const int m = idx >> 7;
    const int n0 = (idx & 127) * 4;
    const float* zr = &z[(size_t)m * ZD];
    float4 a = *reinterpret_cast<const float4*>(&bd1[n0]);
    #pragma unroll
    for (int k = 0; k < ZD; ++k) {
        const float zk = zr[k];
        float4 w = *reinterpret_cast<const float4*>(&Wd1[(size_t)k * HDIM + n0]);
        a.x += zk * w.x; a.y += zk * w.y; a.z += zk * w.z; a.w += zk * w.w;
    }
    ushort4 o;
    o.x = f2bf(fmaxf(a.x, 0.f));
    o.y = f2bf(fmaxf(a.y, 0.f));
    o.z = f2bf(fmaxf(a.z, 0.f));
    o.w = f2bf(fmaxf(a.w, 0.f));
    *reinterpret_cast<ushort4*>(&hd[(size_t)m * HDIM + n0]) = o;
}

// ---------------------------------------------------------------------------
// Decoder GEMM with T4 counted-vmcnt pipeline: recon = sigmoid(hd@Wd2+bd2)
// M=32768, N=784(->800), K=512. BM=128, BN=160 (B staged to 192 rows so all
// threads issue exactly 5 global_load_lds per tile -> wave-uniform vmcnt).
// Per K-step: STAGE(t+1) ; vmcnt(5) [tile-t retired, tile-t+1 in flight] ;
// s_barrier ; ds_read+MFMA ; sched_barrier ; s_barrier.
// LDS 40 KB -> 4 blocks/CU.
// ---------------------------------------------------------------------------
#define DBM 128
#define DBN 160
#define DNKT 16

__global__ __launch_bounds__(256)
void decoder_mfma(const unsigned short* __restrict__ hd,
                  const unsigned short* __restrict__ w2tp,
                  const float* __restrict__ bd2,
                  float* __restrict__ recon)
{
    __shared__ __align__(16) unsigned short Al[2][DBM * 32];   // 8 KB each
    __shared__ __align__(16) unsigned short Bl[2][192 * 32];   // 12 KB each

    const int tid = threadIdx.x;
    const int m0 = blockIdx.x * DBM;
    const int n0 = blockIdx.y * DBN;
    const int wave = tid >> 6;
    const int wr = wave >> 1;
    const int wc = wave & 1;
    const int lane = tid & 63;
    const int lr = lane & 15;
    const int kg = lane >> 4;

    const int rS = tid >> 2;               // staging row 0..63
    const int cS = (tid & 3) * 8;          // staging k-chunk (elements)

    f32x4 acc[4][5];
    #pragma unroll
    for (int i = 0; i < 4; ++i)
        #pragma unroll
        for (int j = 0; j < 5; ++j)
            acc[i][j] = (f32x4){0.f, 0.f, 0.f, 0.f};

    // Uniform 5 gloads/thread. B rows 160..191 read allocated-but-unused ws
    // (w2tp buffer spans 832 rows); those LDS rows are never consumed.
    #define DEC_STAGE(b, kt)                                                             \
    {                                                                                    \
        const int k0 = (kt) * 32 + cS;                                                   \
        gload16(&hd[(size_t)(m0 + rS) * HDIM + k0],          &Al[b][(size_t)tid * 8]);   \
        gload16(&hd[(size_t)(m0 + rS + 64) * HDIM + k0],     &Al[b][(size_t)(tid + 256) * 8]); \
        gload16(&w2tp[(size_t)(n0 + rS) * HDIM + k0],        &Bl[b][(size_t)tid * 8]);   \
        gload16(&w2tp[(size_t)(n0 + rS + 64) * HDIM + k0],   &Bl[b][(size_t)(tid + 256) * 8]); \
        gload16(&w2tp[(size_t)(n0 + rS + 128) * HDIM + k0],  &Bl[b][(size_t)(tid + 512) * 8]); \
    }

    DEC_STAGE(0, 0);

    int buf = 0;
    for (int kt = 0; kt < DNKT; ++kt) {
        if (kt + 1 < DNKT) {
            DEC_STAGE(buf ^ 1, kt + 1);
            // wait for tile-kt only; tile-(kt+1)'s 5 loads stay in flight
            asm volatile("s_waitcnt vmcnt(5)" ::: "memory");
        } else {
            asm volatile("s_waitcnt vmcnt(0)" ::: "memory");
        }
        __builtin_amdgcn_s_barrier();          // publish tile-kt to all waves
        __builtin_amdgcn_sched_barrier(0);     // no ds_read hoisted above

        bf16x8 af[4], bfr[5];
        #pragma unroll
        for (int mi = 0; mi < 4; ++mi)
            af[mi] = *reinterpret_cast<const bf16x8*>(
                &Al[buf][(wr * 64 + mi * 16 + lr) * 32 + kg * 8]);
        #pragma unroll
        for (int nf = 0; nf < 5; ++nf)
            bfr[nf] = *reinterpret_cast<const bf16x8*>(
                &Bl[buf][(wc * 80 + nf * 16 + lr) * 32 + kg * 8]);
        #pragma unroll
        for (int mi = 0; mi < 4; ++mi)
            #pragma unroll
            for (int nf = 0; nf < 5; ++nf)
                acc[mi][nf] = __builtin_amdgcn_mfma_f32_16x16x32_bf16(af[mi], bfr[nf], acc[mi][nf], 0, 0, 0);

        __builtin_amdgcn_sched_barrier(0);     // no ds_read sunk below
        __builtin_amdgcn_s_barrier();          // all reads of buf done before overwrite
        buf ^= 1;
    }

    // epilogue: bias + sigmoid (fast rcp), guarded f32 store
    const int mrow = m0 + wr * 64;
    #pragma unroll
    for (int nf = 0; nf < 5; ++nf) {
        const int col = n0 + wc * 80 + nf * 16 + lr;
        if (col < XD) {
            const float bias = bd2[col];
            #pragma unroll
            for (int mi = 0; mi < 4; ++mi) {
                #pragma unroll
                for (int j = 0; j < 4; ++j) {
                    const int row = mrow + mi * 16 + kg * 4 + j;
                    const float v = acc[mi][nf][j] + bias;
                    recon[(size_t)row * XD + col] =
                        __builtin_amdgcn_rcpf(1.f + __expf(-v));
                }
            }
        }
    }
    #undef DEC_STAGE
}

// ---------------------------------------------------------------------------
extern "C" void kernel_launch(void* const* d_in, const int* in_sizes, int n_in,
                              void* d_out, int out_size, void* d_ws, size_t ws_size,
                              hipStream_t stream)
{
    const float* x    = (const float*)d_in[0];
    const float* eps  = (const float*)d_in[1];
    const float* W1   = (const float*)d_in[2];
    const float* b1   = (const float*)d_in[3];
    const float* Wmu  = (const float*)d_in[4];
    const float* bmu  = (const float*)d_in[5];
    const float* Wstd = (const float*)d_in[6];
    const float* bstd = (const float*)d_in[7];
    const float* Wd1  = (const float*)d_in[8];
    const float* bd1  = (const float*)d_in[9];
    const float* Wd2  = (const float*)d_in[10];
    const float* bd2  = (const float*)d_in[11];

    float* out    = (float*)d_out;
    float* recon  = out;
    float* mu     = recon + (size_t)NSAMP * XD;
    float* logvar = mu + (size_t)BATCH * ZS;
    float* zout   = logvar + (size_t)NSAMP * ZD;

    char* wsb = (char*)d_ws;
    unsigned short* hd   = (unsigned short*)wsb;                            // 32 MiB
    unsigned short* x_bf = (unsigned short*)wsb;                            // 6.25 MiB
    unsigned short* h    = (unsigned short*)(wsb + (size_t)68 * 1048576 / 10);
    float*          ms   = (float*)(wsb + (size_t)11 * 1048576);
    unsigned short* w1t  = (unsigned short*)(wsb + (size_t)295 * 1048576 / 10);
    unsigned short* wmst = (unsigned short*)(wsb + (size_t)305 * 1048576 / 10);
    unsigned short* w2tp = (unsigned short*)(wsb + (size_t)32 * 1048576);   // 832x512 bf16 reachable

    prep_kernel<<<7104, 256, 0, stream>>>(W1, x, Wmu, Wstd, Wd2, w1t, x_bf, wmst, w2tp);

    enc_mfma<1><<<dim3(BATCH / 128, HDIM / 128), 256, 0, stream>>>(
        x_bf, w1t, b1, b1, HDIM, h, HDIM, KP1);
    enc_mfma<0><<<dim3(BATCH / 128, NMS / 128), 256, 0, stream>>>(
        h, wmst, bmu, bstd, ZS, ms, NMS, HDIM);

    sample_kernel<<<(BATCH * ZS) / 256, 256, 0, stream>>>(ms, eps, mu, zout, logvar);

    hd_kernel<<<(NSAMP * 128) / 256, 256, 0, stream>>>(zout, Wd1, bd1, hd);
    decoder_mfma<<<dim3(NSAMP / DBM, NP2 / DBN), 256, 0, stream>>>(hd, w2tp, bd2, recon);
}

// Round 9
// 148.289 us; speedup vs baseline: 1.0785x; 1.0785x over previous
//
#include <hip/hip_runtime.h>
#include <hip/hip_bf16.h>
#include <math.h>

#define BATCH 4096
#define XD    784
#define HDIM  512
#define ZD    16
#define NS    8
#define ZS    128
#define NSAMP (BATCH * NS)   // 32768
#define STDN  (ZD * NS * NS) // 1024
#define KP1   800            // K of enc1, padded 784->800
#define NMS   1152           // 128 (mu) + 1024 (std1)
#define NP2   800            // w2t rows padded 784->800 (5*160)

typedef __attribute__((ext_vector_type(8))) short bf16x8;
typedef __attribute__((ext_vector_type(4))) float f32x4;

__device__ inline unsigned short f2bf(float f) {
    unsigned int u = __float_as_uint(f);
    unsigned int r = (u + 0x7fffu + ((u >> 16) & 1u)) >> 16;
    return (unsigned short)r;
}

// HBM -> LDS direct 16B async copy (global_load_lds_dwordx4).
__device__ __forceinline__ void gload16(const unsigned short* g, unsigned short* l) {
    __builtin_amdgcn_global_load_lds(
        (const __attribute__((address_space(1))) unsigned int*)g,
        (__attribute__((address_space(3))) unsigned int*)l,
        16, 0, 0);
}

// ---------------------------------------------------------------------------
// Merged prep (unchanged): block ranges
//   [0,1600)    : W1^T   -> w1t [512][800]
//   [1600,3200) : xpad   -> x_bf [4096][800]
//   [3200,5504) : [Wmu|Wstd]^T -> wmst [1152][512]
//   [5504,7104) : Wd2^T  -> w2tp [800][512] (rows>=784 zero)
// ---------------------------------------------------------------------------
__global__ __launch_bounds__(256)
void prep_kernel(const float* __restrict__ W1, const float* __restrict__ x,
                 const float* __restrict__ Wmu, const float* __restrict__ Wstd,
                 const float* __restrict__ Wd2,
                 unsigned short* __restrict__ w1t, unsigned short* __restrict__ x_bf,
                 unsigned short* __restrict__ wmst, unsigned short* __restrict__ w2tp)
{
    __shared__ unsigned short t[16][17];
    const int tid = threadIdx.x;
    const int tx = tid & 15, ty = tid >> 4;
    const int bid = blockIdx.x;

    if (bid < 1600) {                      // W1^T (K=784 -> 800, N=512)
        const int bx = bid & 31, by = bid >> 5;        // 32 x 50
        const int n = bx * 16 + tx, k = by * 16 + ty;
        t[ty][tx] = (k < XD) ? f2bf(W1[(size_t)k * HDIM + n]) : (unsigned short)0;
        __syncthreads();
        w1t[(size_t)(bx * 16 + ty) * KP1 + (by * 16 + tx)] = t[tx][ty];
    } else if (bid < 3200) {               // xpad
        const int idx = (bid - 1600) * 256 + tid;
        const int row = idx / 100;
        const int c8 = idx - row * 100;
        const int k0 = c8 * 8;
        ushort4 o0 = {0, 0, 0, 0}, o1 = {0, 0, 0, 0};
        if (k0 < XD) {
            const float4 a = *reinterpret_cast<const float4*>(&x[(size_t)row * XD + k0]);
            const float4 b = *reinterpret_cast<const float4*>(&x[(size_t)row * XD + k0 + 4]);
            o0.x = f2bf(a.x); o0.y = f2bf(a.y); o0.z = f2bf(a.z); o0.w = f2bf(a.w);
            o1.x = f2bf(b.x); o1.y = f2bf(b.y); o1.z = f2bf(b.z); o1.w = f2bf(b.w);
        }
        *reinterpret_cast<ushort4*>(&x_bf[(size_t)row * KP1 + k0]) = o0;
        *reinterpret_cast<ushort4*>(&x_bf[(size_t)row * KP1 + k0 + 4]) = o1;
    } else if (bid < 5504) {               // [Wmu|Wstd]^T (N=1152, K=512)
        const int b = bid - 3200;                      // 72 x 32
        const int bx = b % 72, by = b / 72;
        const int n = bx * 16 + tx, k = by * 16 + ty;
        const float v = (n < ZS) ? Wmu[(size_t)k * ZS + n]
                                 : Wstd[(size_t)k * STDN + (n - ZS)];
        t[ty][tx] = f2bf(v);
        __syncthreads();
        wmst[(size_t)(bx * 16 + ty) * HDIM + (by * 16 + tx)] = t[tx][ty];
    } else {                               // Wd2^T (N=784 -> 800 rows, K=512)
        const int b = bid - 5504;                      // 50 x 32
        const int bx = b % 50, by = b / 50;
        const int n = bx * 16 + tx, k = by * 16 + ty;
        t[ty][tx] = (n < XD) ? f2bf(Wd2[(size_t)k * XD + n]) : (unsigned short)0;
        __syncthreads();
        w2tp[(size_t)(bx * 16 + ty) * HDIM + (by * 16 + tx)] = t[tx][ty];
    }
}

// ---------------------------------------------------------------------------
// Encoder MFMA GEMM with LDS-staged coalesced epilogue.
// out = [relu](A @ Bt^T + bias). BM=BN=128, BK=32, 4 waves.
// ---------------------------------------------------------------------------
#define EEBLD 132    // epilogue buffer stride (2-way bank alias only)

template<int OUT_BF16>
__global__ __launch_bounds__(256)
void enc_mfma(const unsigned short* __restrict__ A,
              const unsigned short* __restrict__ Bt,
              const float* __restrict__ bias0, const float* __restrict__ bias1,
              int bsplit, void* __restrict__ Cout, int ldc, int K)
{
    // staging: Al 2x8KB @0, Bl 2x8KB @16K (32KB); epilogue eb 64x132 f32 (33.8KB)
    __shared__ __align__(16) char smem[64 * EEBLD * 4];
    unsigned short* Alb = (unsigned short*)smem;            // [2][128*32]
    unsigned short* Blb = (unsigned short*)(smem + 16384);  // [2][128*32]
    float* eb = (float*)smem;

    const int tid = threadIdx.x;
    const int m0 = blockIdx.x * 128;
    const int n0 = blockIdx.y * 128;
    const int wave = tid >> 6;
    const int lane = tid & 63;
    const int lr = lane & 15;
    const int kg = lane >> 4;
    const int nkt = K >> 5;

    const int rS = tid >> 2;
    const int cS = (tid & 3) * 8;

    f32x4 acc[2][8];
    #pragma unroll
    for (int i = 0; i < 2; ++i)
        #pragma unroll
        for (int j = 0; j < 8; ++j)
            acc[i][j] = (f32x4){0.f, 0.f, 0.f, 0.f};

    #define ENC_STAGE(b, kt)                                                          \
    {                                                                                 \
        const int k0 = (kt) * 32 + cS;                                                \
        gload16(&A[(size_t)(m0 + rS) * K + k0],       &Alb[(b) * 4096 + tid * 8]);    \
        gload16(&A[(size_t)(m0 + rS + 64) * K + k0],  &Alb[(b) * 4096 + (tid + 256) * 8]); \
        gload16(&Bt[(size_t)(n0 + rS) * K + k0],      &Blb[(b) * 4096 + tid * 8]);    \
        gload16(&Bt[(size_t)(n0 + rS + 64) * K + k0], &Blb[(b) * 4096 + (tid + 256) * 8]); \
    }

    ENC_STAGE(0, 0);
    __syncthreads();

    int buf = 0;
    for (int kt = 0; kt < nkt; ++kt) {
        if (kt + 1 < nkt) ENC_STAGE(buf ^ 1, kt + 1);

        bf16x8 af[2], bfr[8];
        #pragma unroll
        for (int mi = 0; mi < 2; ++mi)
            af[mi] = *reinterpret_cast<const bf16x8*>(
                &Alb[buf * 4096 + (wave * 32 + mi * 16 + lr) * 32 + kg * 8]);
        #pragma unroll
        for (int nf = 0; nf < 8; ++nf)
            bfr[nf] = *reinterpret_cast<const bf16x8*>(
                &Blb[buf * 4096 + (nf * 16 + lr) * 32 + kg * 8]);
        #pragma unroll
        for (int mi = 0; mi < 2; ++mi)
            #pragma unroll
            for (int nf = 0; nf < 8; ++nf)
                acc[mi][nf] = __builtin_amdgcn_mfma_f32_16x16x32_bf16(af[mi], bfr[nf], acc[mi][nf], 0, 0, 0);

        __syncthreads();
        buf ^= 1;
    }

    // ---- LDS-staged coalesced epilogue: 2 slices of 64 rows x 128 cols
    #pragma unroll
    for (int mi = 0; mi < 2; ++mi) {
        __syncthreads();
        #pragma unroll
        for (int nf = 0; nf < 8; ++nf) {
            const int ci = nf * 16 + lr;
            const int col = n0 + ci;
            const float bb = (col < bsplit) ? bias0[col] : bias1[col - bsplit];
            #pragma unroll
            for (int j = 0; j < 4; ++j) {
                const int ri = wave * 16 + kg * 4 + j;
                float v = acc[mi][nf][j] + bb;
                if (OUT_BF16) v = fmaxf(v, 0.f);
                eb[ri * EEBLD + ci] = v;
            }
        }
        __syncthreads();
        #pragma unroll
        for (int e = 0; e < 8; ++e) {
            const int q = e * 256 + tid;         // 0..2047
            const int ri = q >> 5;               // 0..63
            const int c4 = (q & 31) * 4;         // 0..124
            const int grow = m0 + (ri >> 4) * 32 + mi * 16 + (ri & 15);
            const float4 v = *reinterpret_cast<const float4*>(&eb[ri * EEBLD + c4]);
            if (OUT_BF16) {
                ushort4 o;
                o.x = f2bf(v.x); o.y = f2bf(v.y); o.z = f2bf(v.z); o.w = f2bf(v.w);
                *reinterpret_cast<ushort4*>(
                    &((unsigned short*)Cout)[(size_t)grow * ldc + n0 + c4]) = o;
            } else {
                *reinterpret_cast<float4*>(
                    &((float*)Cout)[(size_t)grow * ldc + n0 + c4]) = v;
            }
        }
    }
    #undef ENC_STAGE
}

// ---------------------------------------------------------------------------
// Sparse sample (unchanged).
// ---------------------------------------------------------------------------
__global__ __launch_bounds__(256)
void sample_kernel(const float* __restrict__ ms, const float* __restrict__ eps,
                   float* __restrict__ mu_out,
                   float* __restrict__ z_out, float* __restrict__ logvar_out)
{
    const int idx = blockIdx.x * 256 + threadIdx.x;
    const int b = idx >> 7;
    const int r = idx & 127;
    const int d = r & 15;
    const int s1 = r >> 4;

    const float* v = &ms[(size_t)b * NMS + ZS + r * NS];
    const float* e = &eps[(size_t)b * ZS + d];
    float zacc = 0.f, dacc = 0.f;
    #pragma unroll
    for (int k = 0; k < NS; ++k) {
        const float vv = v[k];
        zacc += vv * e[16 * k];
        dacc += vv * vv;
    }
    const float muv = ms[(size_t)b * NMS + r];
    mu_out[(size_t)b * ZS + r] = muv;
    const float zv = muv + zacc;
    const size_t orow = (size_t)(b * NS + s1) * ZD + d;
    z_out[orow] = zv;
    logvar_out[orow] = logf(dacc);
}

// ---------------------------------------------------------------------------
// hd = relu(z @ Wd1 + bd1) in bf16 (unchanged; stores already 8B coalesced).
// ---------------------------------------------------------------------------
__global__ __launch_bounds__(256)
void hd_kernel(const float* __restrict__ z, const float* __restrict__ Wd1,
               const float* __restrict__ bd1, unsigned short* __restrict__ hd)
{
    const int idx = blockIdx.x * 256 + threadIdx.x;
    const int m = idx >> 7;
    const int n0 = (idx & 127) * 4;
    const float* zr = &z[(size_t)m * ZD];
    float4 a = *reinterpret_cast<const float4*>(&bd1[n0]);
    #pragma unroll
    for (int k = 0; k < ZD; ++k) {
        const float zk = zr[k];
        float4 w = *reinterpret_cast<const float4*>(&Wd1[(size_t)k * HDIM + n0]);
        a.x += zk * w.x; a.y += zk * w.y; a.z += zk * w.z; a.w += zk * w.w;
    }
    ushort4 o;
    o.x = f2bf(fmaxf(a.x, 0.f));
    o.y = f2bf(fmaxf(a.y, 0.f));
    o.z = f2bf(fmaxf(a.z, 0.f));
    o.w = f2bf(fmaxf(a.w, 0.f));
    *reinterpret_cast<ushort4*>(&hd[(size_t)m * HDIM + n0]) = o;
}

// ---------------------------------------------------------------------------
// Decoder GEMM (R8 loop) + LDS-staged coalesced epilogue.
// recon = sigmoid(hd@Wd2+bd2). M=32768, N=784(->800), K=512.
// BM=128, BN=160 (192-row uniform staging), 4 waves 2x2 (64x80 each).
// ---------------------------------------------------------------------------
#define DBM 128
#define DBN 160
#define DNKT 16
#define DEBLD 164    // epilogue buffer stride

__global__ __launch_bounds__(256)
void decoder_mfma(const unsigned short* __restrict__ hd,
                  const unsigned short* __restrict__ w2tp,
                  const float* __restrict__ bd2,
                  float* __restrict__ recon)
{
    // staging: Al 2x8KB @0, Bl 2x12KB @16K (40KB); epilogue eb 32x164 f32 (21KB)
    __shared__ __align__(16) char smem[40960];
    unsigned short* Alb = (unsigned short*)smem;            // [2][128*32]
    unsigned short* Blb = (unsigned short*)(smem + 16384);  // [2][192*32]
    float* eb = (float*)smem;

    const int tid = threadIdx.x;
    const int m0 = blockIdx.x * DBM;
    const int n0 = blockIdx.y * DBN;
    const int wave = tid >> 6;
    const int wr = wave >> 1;
    const int wc = wave & 1;
    const int lane = tid & 63;
    const int lr = lane & 15;
    const int kg = lane >> 4;

    const int rS = tid >> 2;
    const int cS = (tid & 3) * 8;

    f32x4 acc[4][5];
    #pragma unroll
    for (int i = 0; i < 4; ++i)
        #pragma unroll
        for (int j = 0; j < 5; ++j)
            acc[i][j] = (f32x4){0.f, 0.f, 0.f, 0.f};

    #define DEC_STAGE(b, kt)                                                             \
    {                                                                                    \
        const int k0 = (kt) * 32 + cS;                                                   \
        gload16(&hd[(size_t)(m0 + rS) * HDIM + k0],          &Alb[(b) * 4096 + tid * 8]); \
        gload16(&hd[(size_t)(m0 + rS + 64) * HDIM + k0],     &Alb[(b) * 4096 + (tid + 256) * 8]); \
        gload16(&w2tp[(size_t)(n0 + rS) * HDIM + k0],        &Blb[(b) * 6144 + tid * 8]); \
        gload16(&w2tp[(size_t)(n0 + rS + 64) * HDIM + k0],   &Blb[(b) * 6144 + (tid + 256) * 8]); \
        gload16(&w2tp[(size_t)(n0 + rS + 128) * HDIM + k0],  &Blb[(b) * 6144 + (tid + 512) * 8]); \
    }

    DEC_STAGE(0, 0);

    int buf = 0;
    for (int kt = 0; kt < DNKT; ++kt) {
        if (kt + 1 < DNKT) {
            DEC_STAGE(buf ^ 1, kt + 1);
            asm volatile("s_waitcnt vmcnt(5)" ::: "memory");
        } else {
            asm volatile("s_waitcnt vmcnt(0)" ::: "memory");
        }
        __builtin_amdgcn_s_barrier();
        __builtin_amdgcn_sched_barrier(0);

        bf16x8 af[4], bfr[5];
        #pragma unroll
        for (int mi = 0; mi < 4; ++mi)
            af[mi] = *reinterpret_cast<const bf16x8*>(
                &Alb[buf * 4096 + (wr * 64 + mi * 16 + lr) * 32 + kg * 8]);
        #pragma unroll
        for (int nf = 0; nf < 5; ++nf)
            bfr[nf] = *reinterpret_cast<const bf16x8*>(
                &Blb[buf * 6144 + (wc * 80 + nf * 16 + lr) * 32 + kg * 8]);
        #pragma unroll
        for (int mi = 0; mi < 4; ++mi)
            #pragma unroll
            for (int nf = 0; nf < 5; ++nf)
                acc[mi][nf] = __builtin_amdgcn_mfma_f32_16x16x32_bf16(af[mi], bfr[nf], acc[mi][nf], 0, 0, 0);

        __builtin_amdgcn_sched_barrier(0);
        __builtin_amdgcn_s_barrier();
        buf ^= 1;
    }

    // ---- LDS-staged coalesced epilogue: 4 slices of 32 rows x 160 cols
    #pragma unroll
    for (int mi = 0; mi < 4; ++mi) {
        __syncthreads();
        #pragma unroll
        for (int nf = 0; nf < 5; ++nf) {
            const int ci = wc * 80 + nf * 16 + lr;
            const int col = n0 + ci;
            const float bb = (col < XD) ? bd2[col] : 0.f;
            #pragma unroll
            for (int j = 0; j < 4; ++j) {
                const int ri = wr * 16 + kg * 4 + j;
                const float v = acc[mi][nf][j] + bb;
                eb[ri * DEBLD + ci] = __builtin_amdgcn_rcpf(1.f + __expf(-v));
            }
        }
        __syncthreads();
        #pragma unroll
        for (int e = 0; e < 5; ++e) {
            const int q = e * 256 + tid;         // 0..1279
            const int ri = q / 40;               // 0..31
            const int c4 = (q - ri * 40) * 4;    // 0..156
            const int col = n0 + c4;
            if (col < XD) {                      // 784%4==0: full float4 valid
                const int grow = m0 + (ri >> 4) * 64 + mi * 16 + (ri & 15);
                *reinterpret_cast<float4*>(&recon[(size_t)grow * XD + col]) =
                    *reinterpret_cast<const float4*>(&eb[ri * DEBLD + c4]);
            }
        }
    }
    #undef DEC_STAGE
}

// ---------------------------------------------------------------------------
extern "C" void kernel_launch(void* const* d_in, const int* in_sizes, int n_in,
                              void* d_out, int out_size, void* d_ws, size_t ws_size,
                              hipStream_t stream)
{
    const float* x    = (const float*)d_in[0];
    const float* eps  = (const float*)d_in[1];
    const float* W1   = (const float*)d_in[2];
    const float* b1   = (const float*)d_in[3];
    const float* Wmu  = (const float*)d_in[4];
    const float* bmu  = (const float*)d_in[5];
    const float* Wstd = (const float*)d_in[6];
    const float* bstd = (const float*)d_in[7];
    const float* Wd1  = (const float*)d_in[8];
    const float* bd1  = (const float*)d_in[9];
    const float* Wd2  = (const float*)d_in[10];
    const float* bd2  = (const float*)d_in[11];

    float* out    = (float*)d_out;
    float* recon  = out;
    float* mu     = recon + (size_t)NSAMP * XD;
    float* logvar = mu + (size_t)BATCH * ZS;
    float* zout   = logvar + (size_t)NSAMP * ZD;

    char* wsb = (char*)d_ws;
    unsigned short* hd   = (unsigned short*)wsb;                            // 32 MiB
    unsigned short* x_bf = (unsigned short*)wsb;                            // 6.25 MiB
    unsigned short* h    = (unsigned short*)(wsb + (size_t)68 * 1048576 / 10);
    float*          ms   = (float*)(wsb + (size_t)11 * 1048576);
    unsigned short* w1t  = (unsigned short*)(wsb + (size_t)295 * 1048576 / 10);
    unsigned short* wmst = (unsigned short*)(wsb + (size_t)305 * 1048576 / 10);
    unsigned short* w2tp = (unsigned short*)(wsb + (size_t)32 * 1048576);   // 832x512 bf16 reachable

    prep_kernel<<<7104, 256, 0, stream>>>(W1, x, Wmu, Wstd, Wd2, w1t, x_bf, wmst, w2tp);

    enc_mfma<1><<<dim3(BATCH / 128, HDIM / 128), 256, 0, stream>>>(
        x_bf, w1t, b1, b1, HDIM, h, HDIM, KP1);
    enc_mfma<0><<<dim3(BATCH / 128, NMS / 128), 256, 0, stream>>>(
        h, wmst, bmu, bstd, ZS, ms, NMS, HDIM);

    sample_kernel<<<(BATCH * ZS) / 256, 256, 0, stream>>>(ms, eps, mu, zout, logvar);

    hd_kernel<<<(NSAMP * 128) / 256, 256, 0, stream>>>(zout, Wd1, bd1, hd);
    decoder_mfma<<<dim3(NSAMP / DBM, NP2 / DBN), 256, 0, stream>>>(hd, w2tp, bd2, recon);
}

// Round 10
// 136.209 us; speedup vs baseline: 1.1742x; 1.0887x over previous
//
#include <hip/hip_runtime.h>
#include <hip/hip_bf16.h>
#include <math.h>

#define BATCH 4096
#define XD    784
#define HDIM  512
#define ZD    16
#define NS    8
#define ZS    128
#define NSAMP (BATCH * NS)   // 32768
#define STDN  (ZD * NS * NS) // 1024
#define KP1   800            // K of enc1, padded 784->800
#define NMS   1152           // 128 (mu) + 1024 (std1)

typedef __attribute__((ext_vector_type(8))) short bf16x8;
typedef __attribute__((ext_vector_type(4))) float f32x4;

__device__ inline unsigned short f2bf(float f) {
    unsigned int u = __float_as_uint(f);
    unsigned int r = (u + 0x7fffu + ((u >> 16) & 1u)) >> 16;
    return (unsigned short)r;
}

// HBM -> LDS direct 16B async copy (global_load_lds_dwordx4).
__device__ __forceinline__ void gload16(const unsigned short* g, unsigned short* l) {
    __builtin_amdgcn_global_load_lds(
        (const __attribute__((address_space(1))) unsigned int*)g,
        (__attribute__((address_space(3))) unsigned int*)l,
        16, 0, 0);
}

// ---------------------------------------------------------------------------
// Merged prep (unchanged): W1^T, xpad, [Wmu|Wstd]^T, Wd2^T(row-padded)
// ---------------------------------------------------------------------------
__global__ __launch_bounds__(256)
void prep_kernel(const float* __restrict__ W1, const float* __restrict__ x,
                 const float* __restrict__ Wmu, const float* __restrict__ Wstd,
                 const float* __restrict__ Wd2,
                 unsigned short* __restrict__ w1t, unsigned short* __restrict__ x_bf,
                 unsigned short* __restrict__ wmst, unsigned short* __restrict__ w2tp)
{
    __shared__ unsigned short t[16][17];
    const int tid = threadIdx.x;
    const int tx = tid & 15, ty = tid >> 4;
    const int bid = blockIdx.x;

    if (bid < 1600) {                      // W1^T (K=784 -> 800, N=512)
        const int bx = bid & 31, by = bid >> 5;
        const int n = bx * 16 + tx, k = by * 16 + ty;
        t[ty][tx] = (k < XD) ? f2bf(W1[(size_t)k * HDIM + n]) : (unsigned short)0;
        __syncthreads();
        w1t[(size_t)(bx * 16 + ty) * KP1 + (by * 16 + tx)] = t[tx][ty];
    } else if (bid < 3200) {               // xpad
        const int idx = (bid - 1600) * 256 + tid;
        const int row = idx / 100;
        const int c8 = idx - row * 100;
        const int k0 = c8 * 8;
        ushort4 o0 = {0, 0, 0, 0}, o1 = {0, 0, 0, 0};
        if (k0 < XD) {
            const float4 a = *reinterpret_cast<const float4*>(&x[(size_t)row * XD + k0]);
            const float4 b = *reinterpret_cast<const float4*>(&x[(size_t)row * XD + k0 + 4]);
            o0.x = f2bf(a.x); o0.y = f2bf(a.y); o0.z = f2bf(a.z); o0.w = f2bf(a.w);
            o1.x = f2bf(b.x); o1.y = f2bf(b.y); o1.z = f2bf(b.z); o1.w = f2bf(b.w);
        }
        *reinterpret_cast<ushort4*>(&x_bf[(size_t)row * KP1 + k0]) = o0;
        *reinterpret_cast<ushort4*>(&x_bf[(size_t)row * KP1 + k0 + 4]) = o1;
    } else if (bid < 5504) {               // [Wmu|Wstd]^T (N=1152, K=512)
        const int b = bid - 3200;
        const int bx = b % 72, by = b / 72;
        const int n = bx * 16 + tx, k = by * 16 + ty;
        const float v = (n < ZS) ? Wmu[(size_t)k * ZS + n]
                                 : Wstd[(size_t)k * STDN + (n - ZS)];
        t[ty][tx] = f2bf(v);
        __syncthreads();
        wmst[(size_t)(bx * 16 + ty) * HDIM + (by * 16 + tx)] = t[tx][ty];
    } else {                               // Wd2^T (N=784 -> 800+ rows, K=512)
        const int b = bid - 5504;
        const int bx = b % 50, by = b / 50;
        const int n = bx * 16 + tx, k = by * 16 + ty;
        t[ty][tx] = (n < XD) ? f2bf(Wd2[(size_t)k * XD + n]) : (unsigned short)0;
        __syncthreads();
        w2tp[(size_t)(bx * 16 + ty) * HDIM + (by * 16 + tx)] = t[tx][ty];
    }
}

// ---------------------------------------------------------------------------
// Encoder MFMA GEMM with LDS-staged coalesced epilogue (unchanged from R9).
// ---------------------------------------------------------------------------
#define EEBLD 132

template<int OUT_BF16>
__global__ __launch_bounds__(256)
void enc_mfma(const unsigned short* __restrict__ A,
              const unsigned short* __restrict__ Bt,
              const float* __restrict__ bias0, const float* __restrict__ bias1,
              int bsplit, void* __restrict__ Cout, int ldc, int K)
{
    __shared__ __align__(16) char smem[64 * EEBLD * 4];
    unsigned short* Alb = (unsigned short*)smem;
    unsigned short* Blb = (unsigned short*)(smem + 16384);
    float* eb = (float*)smem;

    const int tid = threadIdx.x;
    const int m0 = blockIdx.x * 128;
    const int n0 = blockIdx.y * 128;
    const int wave = tid >> 6;
    const int lane = tid & 63;
    const int lr = lane & 15;
    const int kg = lane >> 4;
    const int nkt = K >> 5;

    const int rS = tid >> 2;
    const int cS = (tid & 3) * 8;

    f32x4 acc[2][8];
    #pragma unroll
    for (int i = 0; i < 2; ++i)
        #pragma unroll
        for (int j = 0; j < 8; ++j)
            acc[i][j] = (f32x4){0.f, 0.f, 0.f, 0.f};

    #define ENC_STAGE(b, kt)                                                          \
    {                                                                                 \
        const int k0 = (kt) * 32 + cS;                                                \
        gload16(&A[(size_t)(m0 + rS) * K + k0],       &Alb[(b) * 4096 + tid * 8]);    \
        gload16(&A[(size_t)(m0 + rS + 64) * K + k0],  &Alb[(b) * 4096 + (tid + 256) * 8]); \
        gload16(&Bt[(size_t)(n0 + rS) * K + k0],      &Blb[(b) * 4096 + tid * 8]);    \
        gload16(&Bt[(size_t)(n0 + rS + 64) * K + k0], &Blb[(b) * 4096 + (tid + 256) * 8]); \
    }

    ENC_STAGE(0, 0);
    __syncthreads();

    int buf = 0;
    for (int kt = 0; kt < nkt; ++kt) {
        if (kt + 1 < nkt) ENC_STAGE(buf ^ 1, kt + 1);

        bf16x8 af[2], bfr[8];
        #pragma unroll
        for (int mi = 0; mi < 2; ++mi)
            af[mi] = *reinterpret_cast<const bf16x8*>(
                &Alb[buf * 4096 + (wave * 32 + mi * 16 + lr) * 32 + kg * 8]);
        #pragma unroll
        for (int nf = 0; nf < 8; ++nf)
            bfr[nf] = *reinterpret_cast<const bf16x8*>(
                &Blb[buf * 4096 + (nf * 16 + lr) * 32 + kg * 8]);
        #pragma unroll
        for (int mi = 0; mi < 2; ++mi)
            #pragma unroll
            for (int nf = 0; nf < 8; ++nf)
                acc[mi][nf] = __builtin_amdgcn_mfma_f32_16x16x32_bf16(af[mi], bfr[nf], acc[mi][nf], 0, 0, 0);

        __syncthreads();
        buf ^= 1;
    }

    #pragma unroll
    for (int mi = 0; mi < 2; ++mi) {
        __syncthreads();
        #pragma unroll
        for (int nf = 0; nf < 8; ++nf) {
            const int ci = nf * 16 + lr;
            const int col = n0 + ci;
            const float bb = (col < bsplit) ? bias0[col] : bias1[col - bsplit];
            #pragma unroll
            for (int j = 0; j < 4; ++j) {
                const int ri = wave * 16 + kg * 4 + j;
                float v = acc[mi][nf][j] + bb;
                if (OUT_BF16) v = fmaxf(v, 0.f);
                eb[ri * EEBLD + ci] = v;
            }
        }
        __syncthreads();
        #pragma unroll
        for (int e = 0; e < 8; ++e) {
            const int q = e * 256 + tid;
            const int ri = q >> 5;
            const int c4 = (q & 31) * 4;
            const int grow = m0 + (ri >> 4) * 32 + mi * 16 + (ri & 15);
            const float4 v = *reinterpret_cast<const float4*>(&eb[ri * EEBLD + c4]);
            if (OUT_BF16) {
                ushort4 o;
                o.x = f2bf(v.x); o.y = f2bf(v.y); o.z = f2bf(v.z); o.w = f2bf(v.w);
                *reinterpret_cast<ushort4*>(
                    &((unsigned short*)Cout)[(size_t)grow * ldc + n0 + c4]) = o;
            } else {
                *reinterpret_cast<float4*>(
                    &((float*)Cout)[(size_t)grow * ldc + n0 + c4]) = v;
            }
        }
    }
    #undef ENC_STAGE
}

// ---------------------------------------------------------------------------
// Fused sample + hd: per block 2 batch rows.
// Phase 1: z = mu + A@eps, logvar, mu copy-out; z kept in LDS.
// Phase 2: hd = relu(z @ Wd1 + bd1) -> bf16 (16 z-rows x 512 cols).
// ---------------------------------------------------------------------------
__global__ __launch_bounds__(256)
void samphd_kernel(const float* __restrict__ ms, const float* __restrict__ eps,
                   const float* __restrict__ Wd1, const float* __restrict__ bd1,
                   float* __restrict__ mu_out, float* __restrict__ z_out,
                   float* __restrict__ logvar_out, unsigned short* __restrict__ hd)
{
    __shared__ float zsh[16][16];
    const int tid = threadIdx.x;
    const int b0 = blockIdx.x * 2;
    const int b = b0 + (tid >> 7);
    const int r = tid & 127;
    const int d = r & 15;
    const int s1 = r >> 4;

    // phase 1: sparse sample
    {
        const float* v = &ms[(size_t)b * NMS + ZS + r * NS];
        const float* e = &eps[(size_t)b * ZS + d];
        float zacc = 0.f, dacc = 0.f;
        #pragma unroll
        for (int k = 0; k < NS; ++k) {
            const float vv = v[k];
            zacc += vv * e[16 * k];
            dacc += vv * vv;
        }
        const float muv = ms[(size_t)b * NMS + r];
        mu_out[(size_t)b * ZS + r] = muv;
        const float zv = muv + zacc;
        const size_t orow = (size_t)(b * NS + s1) * ZD + d;
        z_out[orow] = zv;
        logvar_out[orow] = logf(dacc);
        zsh[(tid >> 7) * 8 + s1][d] = zv;
    }
    __syncthreads();

    // phase 2: hd rows b0*8 .. b0*8+15
    for (int e2 = 0; e2 < 8; ++e2) {
        const int q = e2 * 256 + tid;        // 0..2047
        const int zr = q >> 7;               // 0..15
        const int n0 = (q & 127) * 4;
        float4 a = *reinterpret_cast<const float4*>(&bd1[n0]);
        #pragma unroll
        for (int k = 0; k < ZD; ++k) {
            const float zk = zsh[zr][k];
            const float4 w = *reinterpret_cast<const float4*>(&Wd1[(size_t)k * HDIM + n0]);
            a.x += zk * w.x; a.y += zk * w.y; a.z += zk * w.z; a.w += zk * w.w;
        }
        ushort4 o;
        o.x = f2bf(fmaxf(a.x, 0.f));
        o.y = f2bf(fmaxf(a.y, 0.f));
        o.z = f2bf(fmaxf(a.z, 0.f));
        o.w = f2bf(fmaxf(a.w, 0.f));
        *reinterpret_cast<ushort4*>(&hd[(size_t)(b0 * 8 + zr) * HDIM + n0]) = o;
    }
}

// ---------------------------------------------------------------------------
// Decoder GEMM: recon = sigmoid(hd@Wd2+bd2). M=32768, N=784(->800), K=512.
// BM=64 (grid 512, one block per m-tile), n-chunk loop (5 x 160) INSIDE the
// block so the 64x512 hd tile streams from HBM once and re-reads hit L2.
// Flat 80-tile pipeline (t = nc*16 + kt), uniform 4 gloads/thread, vmcnt(4).
// Waves 2x2: per-wave 32x80, acc[2][5]. Epilogue per chunk into separate eb.
// LDS: A 2x4KB + B 2x12KB + eb 21KB = 53.5 KB.
// ---------------------------------------------------------------------------
#define DNCH 5
#define DNKT 16
#define DEBLD 164

__global__ __launch_bounds__(256)
void decoder_mfma(const unsigned short* __restrict__ hd,
                  const unsigned short* __restrict__ w2tp,
                  const float* __restrict__ bd2,
                  float* __restrict__ recon)
{
    __shared__ __align__(16) char smem[32768 + 32 * DEBLD * 4];
    unsigned short* Alb = (unsigned short*)smem;             // [2][64*32]
    unsigned short* Blb = (unsigned short*)(smem + 8192);    // [2][192*32]
    float* eb = (float*)(smem + 32768);                      // [32][164]

    const int tid = threadIdx.x;
    const int m0 = blockIdx.x * 64;
    const int wave = tid >> 6;
    const int wr = wave >> 1;          // rows wr*32
    const int wc = wave & 1;           // cols wc*80
    const int lane = tid & 63;
    const int lr = lane & 15;
    const int kg = lane >> 4;

    const int rS = tid >> 2;           // 0..63
    const int cS = (tid & 3) * 8;

    f32x4 acc[2][5];
    #pragma unroll
    for (int i = 0; i < 2; ++i)
        #pragma unroll
        for (int j = 0; j < 5; ++j)
            acc[i][j] = (f32x4){0.f, 0.f, 0.f, 0.f};

    // 4 uniform gloads/thread per tile: A 64x32 (1) + B 192x32 (3)
    #define DEC_STAGE(b, nc, kt)                                                          \
    {                                                                                     \
        const int k0 = (kt) * 32 + cS;                                                    \
        const int nb = (nc) * 160;                                                        \
        gload16(&hd[(size_t)(m0 + rS) * HDIM + k0],            &Alb[(b) * 2048 + tid * 8]); \
        gload16(&w2tp[(size_t)(nb + rS) * HDIM + k0],          &Blb[(b) * 6144 + tid * 8]); \
        gload16(&w2tp[(size_t)(nb + rS + 64) * HDIM + k0],     &Blb[(b) * 6144 + (tid + 256) * 8]); \
        gload16(&w2tp[(size_t)(nb + rS + 128) * HDIM + k0],    &Blb[(b) * 6144 + (tid + 512) * 8]); \
    }

    DEC_STAGE(0, 0, 0);

    int buf = 0;
    for (int t = 0; t < DNCH * DNKT; ++t) {
        const int kt = t & 15;
        if (t + 1 < DNCH * DNKT) {
            DEC_STAGE(buf ^ 1, (t + 1) >> 4, (t + 1) & 15);
            asm volatile("s_waitcnt vmcnt(4)" ::: "memory");
        } else {
            asm volatile("s_waitcnt vmcnt(0)" ::: "memory");
        }
        __builtin_amdgcn_s_barrier();
        __builtin_amdgcn_sched_barrier(0);

        bf16x8 af[2], bfr[5];
        #pragma unroll
        for (int mi = 0; mi < 2; ++mi)
            af[mi] = *reinterpret_cast<const bf16x8*>(
                &Alb[buf * 2048 + (wr * 32 + mi * 16 + lr) * 32 + kg * 8]);
        #pragma unroll
        for (int nf = 0; nf < 5; ++nf)
            bfr[nf] = *reinterpret_cast<const bf16x8*>(
                &Blb[buf * 6144 + (wc * 80 + nf * 16 + lr) * 32 + kg * 8]);
        #pragma unroll
        for (int mi = 0; mi < 2; ++mi)
            #pragma unroll
            for (int nf = 0; nf < 5; ++nf)
                acc[mi][nf] = __builtin_amdgcn_mfma_f32_16x16x32_bf16(af[mi], bfr[nf], acc[mi][nf], 0, 0, 0);

        __builtin_amdgcn_sched_barrier(0);
        __builtin_amdgcn_s_barrier();
        buf ^= 1;

        if (kt == 15) {
            // per-chunk epilogue (separate eb; raw barriers with lgkmcnt only,
            // so the in-flight prefetch of the next chunk is NOT drained)
            const int n0 = (t >> 4) * 160;
            #pragma unroll
            for (int s = 0; s < 2; ++s) {
                if (wr == s) {
                    #pragma unroll
                    for (int nf = 0; nf < 5; ++nf) {
                        const int ci = wc * 80 + nf * 16 + lr;
                        const int col = n0 + ci;
                        const float bb = (col < XD) ? bd2[col] : 0.f;
                        #pragma unroll
                        for (int mi = 0; mi < 2; ++mi)
                            #pragma unroll
                            for (int j = 0; j < 4; ++j) {
                                const float v = acc[mi][nf][j] + bb;
                                eb[(mi * 16 + kg * 4 + j) * DEBLD + ci] =
                                    __builtin_amdgcn_rcpf(1.f + __expf(-v));
                            }
                    }
                }
                asm volatile("s_waitcnt lgkmcnt(0)" ::: "memory");
                __builtin_amdgcn_sched_barrier(0);
                __builtin_amdgcn_s_barrier();
                #pragma unroll
                for (int e = 0; e < 5; ++e) {
                    const int q = e * 256 + tid;      // 0..1279
                    const int ri = q / 40;            // 0..31
                    const int c4 = (q - ri * 40) * 4; // 0..156
                    const int col = n0 + c4;
                    if (col < XD) {
                        const int grow = m0 + s * 32 + ri;
                        *reinterpret_cast<float4*>(&recon[(size_t)grow * XD + col]) =
                            *reinterpret_cast<const float4*>(&eb[ri * DEBLD + c4]);
                    }
                }
                asm volatile("s_waitcnt lgkmcnt(0)" ::: "memory");
                __builtin_amdgcn_sched_barrier(0);
                __builtin_amdgcn_s_barrier();
            }
            // reset accumulator for next chunk
            #pragma unroll
            for (int i = 0; i < 2; ++i)
                #pragma unroll
                for (int j = 0; j < 5; ++j)
                    acc[i][j] = (f32x4){0.f, 0.f, 0.f, 0.f};
        }
    }
    #undef DEC_STAGE
}

// ---------------------------------------------------------------------------
extern "C" void kernel_launch(void* const* d_in, const int* in_sizes, int n_in,
                              void* d_out, int out_size, void* d_ws, size_t ws_size,
                              hipStream_t stream)
{
    const float* x    = (const float*)d_in[0];
    const float* eps  = (const float*)d_in[1];
    const float* W1   = (const float*)d_in[2];
    const float* b1   = (const float*)d_in[3];
    const float* Wmu  = (const float*)d_in[4];
    const float* bmu  = (const float*)d_in[5];
    const float* Wstd = (const float*)d_in[6];
    const float* bstd = (const float*)d_in[7];
    const float* Wd1  = (const float*)d_in[8];
    const float* bd1  = (const float*)d_in[9];
    const float* Wd2  = (const float*)d_in[10];
    const float* bd2  = (const float*)d_in[11];

    float* out    = (float*)d_out;
    float* recon  = out;
    float* mu     = recon + (size_t)NSAMP * XD;
    float* logvar = mu + (size_t)BATCH * ZS;
    float* zout   = logvar + (size_t)NSAMP * ZD;

    char* wsb = (char*)d_ws;
    unsigned short* hd   = (unsigned short*)wsb;                            // 32 MiB
    unsigned short* x_bf = (unsigned short*)wsb;                            // 6.25 MiB
    unsigned short* h    = (unsigned short*)(wsb + (size_t)68 * 1048576 / 10);
    float*          ms   = (float*)(wsb + (size_t)11 * 1048576);
    unsigned short* w1t  = (unsigned short*)(wsb + (size_t)295 * 1048576 / 10);
    unsigned short* wmst = (unsigned short*)(wsb + (size_t)305 * 1048576 / 10);
    unsigned short* w2tp = (unsigned short*)(wsb + (size_t)32 * 1048576);   // 832x512 bf16 reachable

    prep_kernel<<<7104, 256, 0, stream>>>(W1, x, Wmu, Wstd, Wd2, w1t, x_bf, wmst, w2tp);

    enc_mfma<1><<<dim3(BATCH / 128, HDIM / 128), 256, 0, stream>>>(
        x_bf, w1t, b1, b1, HDIM, h, HDIM, KP1);
    enc_mfma<0><<<dim3(BATCH / 128, NMS / 128), 256, 0, stream>>>(
        h, wmst, bmu, bstd, ZS, ms, NMS, HDIM);

    samphd_kernel<<<BATCH / 2, 256, 0, stream>>>(ms, eps, Wd1, bd1, mu, zout, logvar, hd);

    decoder_mfma<<<NSAMP / 64, 256, 0, stream>>>(hd, w2tp, bd2, recon);
}

// Round 12
// 115.125 us; speedup vs baseline: 1.3892x; 1.1831x over previous
//
#include <hip/hip_runtime.h>
#include <hip/hip_bf16.h>
#include <math.h>

#define BATCH 4096
#define XD    784
#define HDIM  512
#define ZD    16
#define NS    8
#define ZS    128
#define NSAMP (BATCH * NS)   // 32768
#define STDN  (ZD * NS * NS) // 1024
#define KP1   800            // K of enc1, padded 784->800
#define NMS   1152           // 128 (mu) + 1024 (std1)
#define NP2   800            // w2t rows padded 784->800 (5*160)

typedef __attribute__((ext_vector_type(8))) short bf16x8;
typedef __attribute__((ext_vector_type(4))) float f32x4;

__device__ inline unsigned short f2bf(float f) {
    unsigned int u = __float_as_uint(f);
    unsigned int r = (u + 0x7fffu + ((u >> 16) & 1u)) >> 16;
    return (unsigned short)r;
}

// HBM -> LDS direct 16B async copy (global_load_lds_dwordx4).
__device__ __forceinline__ void gload16(const unsigned short* g, unsigned short* l) {
    __builtin_amdgcn_global_load_lds(
        (const __attribute__((address_space(1))) unsigned int*)g,
        (__attribute__((address_space(3))) unsigned int*)l,
        16, 0, 0);
}

// ---------------------------------------------------------------------------
// Merged prep (unchanged): W1^T, xpad, [Wmu|Wstd]^T, Wd2^T(row-padded)
// ---------------------------------------------------------------------------
__global__ __launch_bounds__(256)
void prep_kernel(const float* __restrict__ W1, const float* __restrict__ x,
                 const float* __restrict__ Wmu, const float* __restrict__ Wstd,
                 const float* __restrict__ Wd2,
                 unsigned short* __restrict__ w1t, unsigned short* __restrict__ x_bf,
                 unsigned short* __restrict__ wmst, unsigned short* __restrict__ w2tp)
{
    __shared__ unsigned short t[16][17];
    const int tid = threadIdx.x;
    const int tx = tid & 15, ty = tid >> 4;
    const int bid = blockIdx.x;

    if (bid < 1600) {                      // W1^T (K=784 -> 800, N=512)
        const int bx = bid & 31, by = bid >> 5;
        const int n = bx * 16 + tx, k = by * 16 + ty;
        t[ty][tx] = (k < XD) ? f2bf(W1[(size_t)k * HDIM + n]) : (unsigned short)0;
        __syncthreads();
        w1t[(size_t)(bx * 16 + ty) * KP1 + (by * 16 + tx)] = t[tx][ty];
    } else if (bid < 3200) {               // xpad
        const int idx = (bid - 1600) * 256 + tid;
        const int row = idx / 100;
        const int c8 = idx - row * 100;
        const int k0 = c8 * 8;
        ushort4 o0 = {0, 0, 0, 0}, o1 = {0, 0, 0, 0};
        if (k0 < XD) {
            const float4 a = *reinterpret_cast<const float4*>(&x[(size_t)row * XD + k0]);
            const float4 b = *reinterpret_cast<const float4*>(&x[(size_t)row * XD + k0 + 4]);
            o0.x = f2bf(a.x); o0.y = f2bf(a.y); o0.z = f2bf(a.z); o0.w = f2bf(a.w);
            o1.x = f2bf(b.x); o1.y = f2bf(b.y); o1.z = f2bf(b.z); o1.w = f2bf(b.w);
        }
        *reinterpret_cast<ushort4*>(&x_bf[(size_t)row * KP1 + k0]) = o0;
        *reinterpret_cast<ushort4*>(&x_bf[(size_t)row * KP1 + k0 + 4]) = o1;
    } else if (bid < 5504) {               // [Wmu|Wstd]^T (N=1152, K=512)
        const int b = bid - 3200;
        const int bx = b % 72, by = b / 72;
        const int n = bx * 16 + tx, k = by * 16 + ty;
        const float v = (n < ZS) ? Wmu[(size_t)k * ZS + n]
                                 : Wstd[(size_t)k * STDN + (n - ZS)];
        t[ty][tx] = f2bf(v);
        __syncthreads();
        wmst[(size_t)(bx * 16 + ty) * HDIM + (by * 16 + tx)] = t[tx][ty];
    } else {                               // Wd2^T (N=784 -> 800+ rows, K=512)
        const int b = bid - 5504;
        const int bx = b % 50, by = b / 50;
        const int n = bx * 16 + tx, k = by * 16 + ty;
        t[ty][tx] = (n < XD) ? f2bf(Wd2[(size_t)k * XD + n]) : (unsigned short)0;
        __syncthreads();
        w2tp[(size_t)(bx * 16 + ty) * HDIM + (by * 16 + tx)] = t[tx][ty];
    }
}

// ---------------------------------------------------------------------------
// Encoder MFMA GEMM with LDS-staged coalesced epilogue (unchanged).
// ---------------------------------------------------------------------------
#define EEBLD 132

template<int OUT_BF16>
__global__ __launch_bounds__(256)
void enc_mfma(const unsigned short* __restrict__ A,
              const unsigned short* __restrict__ Bt,
              const float* __restrict__ bias0, const float* __restrict__ bias1,
              int bsplit, void* __restrict__ Cout, int ldc, int K)
{
    __shared__ __align__(16) char smem[64 * EEBLD * 4];
    unsigned short* Alb = (unsigned short*)smem;
    unsigned short* Blb = (unsigned short*)(smem + 16384);
    float* eb = (float*)smem;

    const int tid = threadIdx.x;
    const int m0 = blockIdx.x * 128;
    const int n0 = blockIdx.y * 128;
    const int wave = tid >> 6;
    const int lane = tid & 63;
    const int lr = lane & 15;
    const int kg = lane >> 4;
    const int nkt = K >> 5;

    const int rS = tid >> 2;
    const int cS = (tid & 3) * 8;

    f32x4 acc[2][8];
    #pragma unroll
    for (int i = 0; i < 2; ++i)
        #pragma unroll
        for (int j = 0; j < 8; ++j)
            acc[i][j] = (f32x4){0.f, 0.f, 0.f, 0.f};

    #define ENC_STAGE(b, kt)                                                          \
    {                                                                                 \
        const int k0 = (kt) * 32 + cS;                                                \
        gload16(&A[(size_t)(m0 + rS) * K + k0],       &Alb[(b) * 4096 + tid * 8]);    \
        gload16(&A[(size_t)(m0 + rS + 64) * K + k0],  &Alb[(b) * 4096 + (tid + 256) * 8]); \
        gload16(&Bt[(size_t)(n0 + rS) * K + k0],      &Blb[(b) * 4096 + tid * 8]);    \
        gload16(&Bt[(size_t)(n0 + rS + 64) * K + k0], &Blb[(b) * 4096 + (tid + 256) * 8]); \
    }

    ENC_STAGE(0, 0);
    __syncthreads();

    int buf = 0;
    for (int kt = 0; kt < nkt; ++kt) {
        if (kt + 1 < nkt) ENC_STAGE(buf ^ 1, kt + 1);

        bf16x8 af[2], bfr[8];
        #pragma unroll
        for (int mi = 0; mi < 2; ++mi)
            af[mi] = *reinterpret_cast<const bf16x8*>(
                &Alb[buf * 4096 + (wave * 32 + mi * 16 + lr) * 32 + kg * 8]);
        #pragma unroll
        for (int nf = 0; nf < 8; ++nf)
            bfr[nf] = *reinterpret_cast<const bf16x8*>(
                &Blb[buf * 4096 + (nf * 16 + lr) * 32 + kg * 8]);
        #pragma unroll
        for (int mi = 0; mi < 2; ++mi)
            #pragma unroll
            for (int nf = 0; nf < 8; ++nf)
                acc[mi][nf] = __builtin_amdgcn_mfma_f32_16x16x32_bf16(af[mi], bfr[nf], acc[mi][nf], 0, 0, 0);

        __syncthreads();
        buf ^= 1;
    }

    #pragma unroll
    for (int mi = 0; mi < 2; ++mi) {
        __syncthreads();
        #pragma unroll
        for (int nf = 0; nf < 8; ++nf) {
            const int ci = nf * 16 + lr;
            const int col = n0 + ci;
            const float bb = (col < bsplit) ? bias0[col] : bias1[col - bsplit];
            #pragma unroll
            for (int j = 0; j < 4; ++j) {
                const int ri = wave * 16 + kg * 4 + j;
                float v = acc[mi][nf][j] + bb;
                if (OUT_BF16) v = fmaxf(v, 0.f);
                eb[ri * EEBLD + ci] = v;
            }
        }
        __syncthreads();
        #pragma unroll
        for (int e = 0; e < 8; ++e) {
            const int q = e * 256 + tid;
            const int ri = q >> 5;
            const int c4 = (q & 31) * 4;
            const int grow = m0 + (ri >> 4) * 32 + mi * 16 + (ri & 15);
            const float4 v = *reinterpret_cast<const float4*>(&eb[ri * EEBLD + c4]);
            if (OUT_BF16) {
                ushort4 o;
                o.x = f2bf(v.x); o.y = f2bf(v.y); o.z = f2bf(v.z); o.w = f2bf(v.w);
                *reinterpret_cast<ushort4*>(
                    &((unsigned short*)Cout)[(size_t)grow * ldc + n0 + c4]) = o;
            } else {
                *reinterpret_cast<float4*>(
                    &((float*)Cout)[(size_t)grow * ldc + n0 + c4]) = v;
            }
        }
    }
    #undef ENC_STAGE
}

// ---------------------------------------------------------------------------
// Fused sample + hd (unchanged).
// ---------------------------------------------------------------------------
__global__ __launch_bounds__(256)
void samphd_kernel(const float* __restrict__ ms, const float* __restrict__ eps,
                   const float* __restrict__ Wd1, const float* __restrict__ bd1,
                   float* __restrict__ mu_out, float* __restrict__ z_out,
                   float* __restrict__ logvar_out, unsigned short* __restrict__ hd)
{
    __shared__ float zsh[16][16];
    const int tid = threadIdx.x;
    const int b0 = blockIdx.x * 2;
    const int b = b0 + (tid >> 7);
    const int r = tid & 127;
    const int d = r & 15;
    const int s1 = r >> 4;

    {
        const float* v = &ms[(size_t)b * NMS + ZS + r * NS];
        const float* e = &eps[(size_t)b * ZS + d];
        float zacc = 0.f, dacc = 0.f;
        #pragma unroll
        for (int k = 0; k < NS; ++k) {
            const float vv = v[k];
            zacc += vv * e[16 * k];
            dacc += vv * vv;
        }
        const float muv = ms[(size_t)b * NMS + r];
        mu_out[(size_t)b * ZS + r] = muv;
        const float zv = muv + zacc;
        const size_t orow = (size_t)(b * NS + s1) * ZD + d;
        z_out[orow] = zv;
        logvar_out[orow] = logf(dacc);
        zsh[(tid >> 7) * 8 + s1][d] = zv;
    }
    __syncthreads();

    for (int e2 = 0; e2 < 8; ++e2) {
        const int q = e2 * 256 + tid;
        const int zr = q >> 7;
        const int n0 = (q & 127) * 4;
        float4 a = *reinterpret_cast<const float4*>(&bd1[n0]);
        #pragma unroll
        for (int k = 0; k < ZD; ++k) {
            const float zk = zsh[zr][k];
            const float4 w = *reinterpret_cast<const float4*>(&Wd1[(size_t)k * HDIM + n0]);
            a.x += zk * w.x; a.y += zk * w.y; a.z += zk * w.z; a.w += zk * w.w;
        }
        ushort4 o;
        o.x = f2bf(fmaxf(a.x, 0.f));
        o.y = f2bf(fmaxf(a.y, 0.f));
        o.z = f2bf(fmaxf(a.z, 0.f));
        o.w = f2bf(fmaxf(a.w, 0.f));
        *reinterpret_cast<ushort4*>(&hd[(size_t)(b0 * 8 + zr) * HDIM + n0]) = o;
    }
}

// ---------------------------------------------------------------------------
// Decoder GEMM: R9 structure + nontemporal recon stores (ext-vector f32x4,
// which __builtin_nontemporal_store accepts).
// BM=128, BN=160 (192-row uniform staging), grid 256x5, vmcnt(5) pipeline,
// coalesced LDS epilogue. LDS 40KB staging + 21KB eb (aliased).
// ---------------------------------------------------------------------------
#define DBM 128
#define DBN 160
#define DNKT 16
#define DEBLD 164

__global__ __launch_bounds__(256)
void decoder_mfma(const unsigned short* __restrict__ hd,
                  const unsigned short* __restrict__ w2tp,
                  const float* __restrict__ bd2,
                  float* __restrict__ recon)
{
    __shared__ __align__(16) char smem[40960];
    unsigned short* Alb = (unsigned short*)smem;            // [2][128*32]
    unsigned short* Blb = (unsigned short*)(smem + 16384);  // [2][192*32]
    float* eb = (float*)smem;

    const int tid = threadIdx.x;
    const int m0 = blockIdx.x * DBM;
    const int n0 = blockIdx.y * DBN;
    const int wave = tid >> 6;
    const int wr = wave >> 1;
    const int wc = wave & 1;
    const int lane = tid & 63;
    const int lr = lane & 15;
    const int kg = lane >> 4;

    const int rS = tid >> 2;
    const int cS = (tid & 3) * 8;

    f32x4 acc[4][5];
    #pragma unroll
    for (int i = 0; i < 4; ++i)
        #pragma unroll
        for (int j = 0; j < 5; ++j)
            acc[i][j] = (f32x4){0.f, 0.f, 0.f, 0.f};

    #define DEC_STAGE(b, kt)                                                             \
    {                                                                                    \
        const int k0 = (kt) * 32 + cS;                                                   \
        gload16(&hd[(size_t)(m0 + rS) * HDIM + k0],          &Alb[(b) * 4096 + tid * 8]); \
        gload16(&hd[(size_t)(m0 + rS + 64) * HDIM + k0],     &Alb[(b) * 4096 + (tid + 256) * 8]); \
        gload16(&w2tp[(size_t)(n0 + rS) * HDIM + k0],        &Blb[(b) * 6144 + tid * 8]); \
        gload16(&w2tp[(size_t)(n0 + rS + 64) * HDIM + k0],   &Blb[(b) * 6144 + (tid + 256) * 8]); \
        gload16(&w2tp[(size_t)(n0 + rS + 128) * HDIM + k0],  &Blb[(b) * 6144 + (tid + 512) * 8]); \
    }

    DEC_STAGE(0, 0);

    int buf = 0;
    for (int kt = 0; kt < DNKT; ++kt) {
        if (kt + 1 < DNKT) {
            DEC_STAGE(buf ^ 1, kt + 1);
            asm volatile("s_waitcnt vmcnt(5)" ::: "memory");
        } else {
            asm volatile("s_waitcnt vmcnt(0)" ::: "memory");
        }
        __builtin_amdgcn_s_barrier();
        __builtin_amdgcn_sched_barrier(0);

        bf16x8 af[4], bfr[5];
        #pragma unroll
        for (int mi = 0; mi < 4; ++mi)
            af[mi] = *reinterpret_cast<const bf16x8*>(
                &Alb[buf * 4096 + (wr * 64 + mi * 16 + lr) * 32 + kg * 8]);
        #pragma unroll
        for (int nf = 0; nf < 5; ++nf)
            bfr[nf] = *reinterpret_cast<const bf16x8*>(
                &Blb[buf * 6144 + (wc * 80 + nf * 16 + lr) * 32 + kg * 8]);
        #pragma unroll
        for (int mi = 0; mi < 4; ++mi)
            #pragma unroll
            for (int nf = 0; nf < 5; ++nf)
                acc[mi][nf] = __builtin_amdgcn_mfma_f32_16x16x32_bf16(af[mi], bfr[nf], acc[mi][nf], 0, 0, 0);

        __builtin_amdgcn_sched_barrier(0);
        __builtin_amdgcn_s_barrier();
        buf ^= 1;
    }

    // ---- LDS-staged coalesced epilogue, nontemporal ext-vector stores
    #pragma unroll
    for (int mi = 0; mi < 4; ++mi) {
        __syncthreads();
        #pragma unroll
        for (int nf = 0; nf < 5; ++nf) {
            const int ci = wc * 80 + nf * 16 + lr;
            const int col = n0 + ci;
            const float bb = (col < XD) ? bd2[col] : 0.f;
            #pragma unroll
            for (int j = 0; j < 4; ++j) {
                const int ri = wr * 16 + kg * 4 + j;
                const float v = acc[mi][nf][j] + bb;
                eb[ri * DEBLD + ci] = __builtin_amdgcn_rcpf(1.f + __expf(-v));
            }
        }
        __syncthreads();
        #pragma unroll
        for (int e = 0; e < 5; ++e) {
            const int q = e * 256 + tid;
            const int ri = q / 40;
            const int c4 = (q - ri * 40) * 4;
            const int col = n0 + c4;
            if (col < XD) {
                const int grow = m0 + (ri >> 4) * 64 + mi * 16 + (ri & 15);
                const f32x4 v = *reinterpret_cast<const f32x4*>(&eb[ri * DEBLD + c4]);
                __builtin_nontemporal_store(
                    v, reinterpret_cast<f32x4*>(&recon[(size_t)grow * XD + col]));
            }
        }
    }
    #undef DEC_STAGE
}

// ---------------------------------------------------------------------------
extern "C" void kernel_launch(void* const* d_in, const int* in_sizes, int n_in,
                              void* d_out, int out_size, void* d_ws, size_t ws_size,
                              hipStream_t stream)
{
    const float* x    = (const float*)d_in[0];
    const float* eps  = (const float*)d_in[1];
    const float* W1   = (const float*)d_in[2];
    const float* b1   = (const float*)d_in[3];
    const float* Wmu  = (const float*)d_in[4];
    const float* bmu  = (const float*)d_in[5];
    const float* Wstd = (const float*)d_in[6];
    const float* bstd = (const float*)d_in[7];
    const float* Wd1  = (const float*)d_in[8];
    const float* bd1  = (const float*)d_in[9];
    const float* Wd2  = (const float*)d_in[10];
    const float* bd2  = (const float*)d_in[11];

    float* out    = (float*)d_out;
    float* recon  = out;
    float* mu     = recon + (size_t)NSAMP * XD;
    float* logvar = mu + (size_t)BATCH * ZS;
    float* zout   = logvar + (size_t)NSAMP * ZD;

    char* wsb = (char*)d_ws;
    unsigned short* hd   = (unsigned short*)wsb;                            // 32 MiB
    unsigned short* x_bf = (unsigned short*)wsb;                            // 6.25 MiB
    unsigned short* h    = (unsigned short*)(wsb + (size_t)68 * 1048576 / 10);
    float*          ms   = (float*)(wsb + (size_t)11 * 1048576);
    unsigned short* w1t  = (unsigned short*)(wsb + (size_t)295 * 1048576 / 10);
    unsigned short* wmst = (unsigned short*)(wsb + (size_t)305 * 1048576 / 10);
    unsigned short* w2tp = (unsigned short*)(wsb + (size_t)32 * 1048576);   // 832x512 bf16 reachable

    prep_kernel<<<7104, 256, 0, stream>>>(W1, x, Wmu, Wstd, Wd2, w1t, x_bf, wmst, w2tp);

    enc_mfma<1><<<dim3(BATCH / 128, HDIM / 128), 256, 0, stream>>>(
        x_bf, w1t, b1, b1, HDIM, h, HDIM, KP1);
    enc_mfma<0><<<dim3(BATCH / 128, NMS / 128), 256, 0, stream>>>(
        h, wmst, bmu, bstd, ZS, ms, NMS, HDIM);

    samphd_kernel<<<BATCH / 2, 256, 0, stream>>>(ms, eps, Wd1, bd1, mu, zout, logvar, hd);

    decoder_mfma<<<dim3(NSAMP / DBM, NP2 / DBN), 256, 0, stream>>>(hd, w2tp, bd2, recon);
}

// Round 13
// 108.222 us; speedup vs baseline: 1.4778x; 1.0638x over previous
//
#include <hip/hip_runtime.h>
#include <hip/hip_bf16.h>
#include <math.h>

#define BATCH 4096
#define XD    784
#define HDIM  512
#define ZD    16
#define NS    8
#define ZS    128
#define NSAMP (BATCH * NS)   // 32768
#define STDN  (ZD * NS * NS) // 1024
#define KP1   800            // K of enc1, padded 784->800
#define NMS   1152           // 128 (mu) + 1024 (std1)
#define NP2   800            // w2t rows padded 784->800 (5*160)

typedef __attribute__((ext_vector_type(8))) short bf16x8;
typedef __attribute__((ext_vector_type(4))) float f32x4;

__device__ inline unsigned short f2bf(float f) {
    unsigned int u = __float_as_uint(f);
    unsigned int r = (u + 0x7fffu + ((u >> 16) & 1u)) >> 16;
    return (unsigned short)r;
}

// HBM -> LDS direct 16B async copy (global_load_lds_dwordx4).
__device__ __forceinline__ void gload16(const unsigned short* g, unsigned short* l) {
    __builtin_amdgcn_global_load_lds(
        (const __attribute__((address_space(1))) unsigned int*)g,
        (__attribute__((address_space(3))) unsigned int*)l,
        16, 0, 0);
}

// ---------------------------------------------------------------------------
// Merged prep (unchanged): W1^T, xpad, [Wmu|Wstd]^T, Wd2^T(row-padded)
// ---------------------------------------------------------------------------
__global__ __launch_bounds__(256)
void prep_kernel(const float* __restrict__ W1, const float* __restrict__ x,
                 const float* __restrict__ Wmu, const float* __restrict__ Wstd,
                 const float* __restrict__ Wd2,
                 unsigned short* __restrict__ w1t, unsigned short* __restrict__ x_bf,
                 unsigned short* __restrict__ wmst, unsigned short* __restrict__ w2tp)
{
    __shared__ unsigned short t[16][17];
    const int tid = threadIdx.x;
    const int tx = tid & 15, ty = tid >> 4;
    const int bid = blockIdx.x;

    if (bid < 1600) {                      // W1^T (K=784 -> 800, N=512)
        const int bx = bid & 31, by = bid >> 5;
        const int n = bx * 16 + tx, k = by * 16 + ty;
        t[ty][tx] = (k < XD) ? f2bf(W1[(size_t)k * HDIM + n]) : (unsigned short)0;
        __syncthreads();
        w1t[(size_t)(bx * 16 + ty) * KP1 + (by * 16 + tx)] = t[tx][ty];
    } else if (bid < 3200) {               // xpad
        const int idx = (bid - 1600) * 256 + tid;
        const int row = idx / 100;
        const int c8 = idx - row * 100;
        const int k0 = c8 * 8;
        ushort4 o0 = {0, 0, 0, 0}, o1 = {0, 0, 0, 0};
        if (k0 < XD) {
            const float4 a = *reinterpret_cast<const float4*>(&x[(size_t)row * XD + k0]);
            const float4 b = *reinterpret_cast<const float4*>(&x[(size_t)row * XD + k0 + 4]);
            o0.x = f2bf(a.x); o0.y = f2bf(a.y); o0.z = f2bf(a.z); o0.w = f2bf(a.w);
            o1.x = f2bf(b.x); o1.y = f2bf(b.y); o1.z = f2bf(b.z); o1.w = f2bf(b.w);
        }
        *reinterpret_cast<ushort4*>(&x_bf[(size_t)row * KP1 + k0]) = o0;
        *reinterpret_cast<ushort4*>(&x_bf[(size_t)row * KP1 + k0 + 4]) = o1;
    } else if (bid < 5504) {               // [Wmu|Wstd]^T (N=1152, K=512)
        const int b = bid - 3200;
        const int bx = b % 72, by = b / 72;
        const int n = bx * 16 + tx, k = by * 16 + ty;
        const float v = (n < ZS) ? Wmu[(size_t)k * ZS + n]
                                 : Wstd[(size_t)k * STDN + (n - ZS)];
        t[ty][tx] = f2bf(v);
        __syncthreads();
        wmst[(size_t)(bx * 16 + ty) * HDIM + (by * 16 + tx)] = t[tx][ty];
    } else {                               // Wd2^T (N=784 -> 800+ rows, K=512)
        const int b = bid - 5504;
        const int bx = b % 50, by = b / 50;
        const int n = bx * 16 + tx, k = by * 16 + ty;
        t[ty][tx] = (n < XD) ? f2bf(Wd2[(size_t)k * XD + n]) : (unsigned short)0;
        __syncthreads();
        w2tp[(size_t)(bx * 16 + ty) * HDIM + (by * 16 + tx)] = t[tx][ty];
    }
}

// ---------------------------------------------------------------------------
// Encoder MFMA GEMM with LDS-staged coalesced epilogue (unchanged).
// ---------------------------------------------------------------------------
#define EEBLD 132

template<int OUT_BF16>
__global__ __launch_bounds__(256)
void enc_mfma(const unsigned short* __restrict__ A,
              const unsigned short* __restrict__ Bt,
              const float* __restrict__ bias0, const float* __restrict__ bias1,
              int bsplit, void* __restrict__ Cout, int ldc, int K)
{
    __shared__ __align__(16) char smem[64 * EEBLD * 4];
    unsigned short* Alb = (unsigned short*)smem;
    unsigned short* Blb = (unsigned short*)(smem + 16384);
    float* eb = (float*)smem;

    const int tid = threadIdx.x;
    const int m0 = blockIdx.x * 128;
    const int n0 = blockIdx.y * 128;
    const int wave = tid >> 6;
    const int lane = tid & 63;
    const int lr = lane & 15;
    const int kg = lane >> 4;
    const int nkt = K >> 5;

    const int rS = tid >> 2;
    const int cS = (tid & 3) * 8;

    f32x4 acc[2][8];
    #pragma unroll
    for (int i = 0; i < 2; ++i)
        #pragma unroll
        for (int j = 0; j < 8; ++j)
            acc[i][j] = (f32x4){0.f, 0.f, 0.f, 0.f};

    #define ENC_STAGE(b, kt)                                                          \
    {                                                                                 \
        const int k0 = (kt) * 32 + cS;                                                \
        gload16(&A[(size_t)(m0 + rS) * K + k0],       &Alb[(b) * 4096 + tid * 8]);    \
        gload16(&A[(size_t)(m0 + rS + 64) * K + k0],  &Alb[(b) * 4096 + (tid + 256) * 8]); \
        gload16(&Bt[(size_t)(n0 + rS) * K + k0],      &Blb[(b) * 4096 + tid * 8]);    \
        gload16(&Bt[(size_t)(n0 + rS + 64) * K + k0], &Blb[(b) * 4096 + (tid + 256) * 8]); \
    }

    ENC_STAGE(0, 0);
    __syncthreads();

    int buf = 0;
    for (int kt = 0; kt < nkt; ++kt) {
        if (kt + 1 < nkt) ENC_STAGE(buf ^ 1, kt + 1);

        bf16x8 af[2], bfr[8];
        #pragma unroll
        for (int mi = 0; mi < 2; ++mi)
            af[mi] = *reinterpret_cast<const bf16x8*>(
                &Alb[buf * 4096 + (wave * 32 + mi * 16 + lr) * 32 + kg * 8]);
        #pragma unroll
        for (int nf = 0; nf < 8; ++nf)
            bfr[nf] = *reinterpret_cast<const bf16x8*>(
                &Blb[buf * 4096 + (nf * 16 + lr) * 32 + kg * 8]);
        #pragma unroll
        for (int mi = 0; mi < 2; ++mi)
            #pragma unroll
            for (int nf = 0; nf < 8; ++nf)
                acc[mi][nf] = __builtin_amdgcn_mfma_f32_16x16x32_bf16(af[mi], bfr[nf], acc[mi][nf], 0, 0, 0);

        __syncthreads();
        buf ^= 1;
    }

    #pragma unroll
    for (int mi = 0; mi < 2; ++mi) {
        __syncthreads();
        #pragma unroll
        for (int nf = 0; nf < 8; ++nf) {
            const int ci = nf * 16 + lr;
            const int col = n0 + ci;
            const float bb = (col < bsplit) ? bias0[col] : bias1[col - bsplit];
            #pragma unroll
            for (int j = 0; j < 4; ++j) {
                const int ri = wave * 16 + kg * 4 + j;
                float v = acc[mi][nf][j] + bb;
                if (OUT_BF16) v = fmaxf(v, 0.f);
                eb[ri * EEBLD + ci] = v;
            }
        }
        __syncthreads();
        #pragma unroll
        for (int e = 0; e < 8; ++e) {
            const int q = e * 256 + tid;
            const int ri = q >> 5;
            const int c4 = (q & 31) * 4;
            const int grow = m0 + (ri >> 4) * 32 + mi * 16 + (ri & 15);
            const float4 v = *reinterpret_cast<const float4*>(&eb[ri * EEBLD + c4]);
            if (OUT_BF16) {
                ushort4 o;
                o.x = f2bf(v.x); o.y = f2bf(v.y); o.z = f2bf(v.z); o.w = f2bf(v.w);
                *reinterpret_cast<ushort4*>(
                    &((unsigned short*)Cout)[(size_t)grow * ldc + n0 + c4]) = o;
            } else {
                *reinterpret_cast<float4*>(
                    &((float*)Cout)[(size_t)grow * ldc + n0 + c4]) = v;
            }
        }
    }
    #undef ENC_STAGE
}

// ---------------------------------------------------------------------------
// Fused sample + hd (unchanged).
// ---------------------------------------------------------------------------
__global__ __launch_bounds__(256)
void samphd_kernel(const float* __restrict__ ms, const float* __restrict__ eps,
                   const float* __restrict__ Wd1, const float* __restrict__ bd1,
                   float* __restrict__ mu_out, float* __restrict__ z_out,
                   float* __restrict__ logvar_out, unsigned short* __restrict__ hd)
{
    __shared__ float zsh[16][16];
    const int tid = threadIdx.x;
    const int b0 = blockIdx.x * 2;
    const int b = b0 + (tid >> 7);
    const int r = tid & 127;
    const int d = r & 15;
    const int s1 = r >> 4;

    {
        const float* v = &ms[(size_t)b * NMS + ZS + r * NS];
        const float* e = &eps[(size_t)b * ZS + d];
        float zacc = 0.f, dacc = 0.f;
        #pragma unroll
        for (int k = 0; k < NS; ++k) {
            const float vv = v[k];
            zacc += vv * e[16 * k];
            dacc += vv * vv;
        }
        const float muv = ms[(size_t)b * NMS + r];
        mu_out[(size_t)b * ZS + r] = muv;
        const float zv = muv + zacc;
        const size_t orow = (size_t)(b * NS + s1) * ZD + d;
        z_out[orow] = zv;
        logvar_out[orow] = logf(dacc);
        zsh[(tid >> 7) * 8 + s1][d] = zv;
    }
    __syncthreads();

    for (int e2 = 0; e2 < 8; ++e2) {
        const int q = e2 * 256 + tid;
        const int zr = q >> 7;
        const int n0 = (q & 127) * 4;
        float4 a = *reinterpret_cast<const float4*>(&bd1[n0]);
        #pragma unroll
        for (int k = 0; k < ZD; ++k) {
            const float zk = zsh[zr][k];
            const float4 w = *reinterpret_cast<const float4*>(&Wd1[(size_t)k * HDIM + n0]);
            a.x += zk * w.x; a.y += zk * w.y; a.z += zk * w.z; a.w += zk * w.w;
        }
        ushort4 o;
        o.x = f2bf(fmaxf(a.x, 0.f));
        o.y = f2bf(fmaxf(a.y, 0.f));
        o.z = f2bf(fmaxf(a.z, 0.f));
        o.w = f2bf(fmaxf(a.w, 0.f));
        *reinterpret_cast<ushort4*>(&hd[(size_t)(b0 * 8 + zr) * HDIM + n0]) = o;
    }
}

// ---------------------------------------------------------------------------
// Decoder GEMM: R12 structure + XCD-aware block swizzle (T1).
// 1-D grid 1280: c=bid&7 (XCD under round-robin), s=bid>>3;
// m_tile = c*32 + s/5, n_chunk = s%5. The 5 n-chunks of one m-tile are
// temporally adjacent ON THE SAME XCD -> the 128KB hd tile stays L2-resident
// across its 5 uses; w2tp (0.8MB) is L2-resident per XCD. Moves ~365MB of
// re-reads from L3 (~6.5TB/s) to L2 (34.5TB/s).
// ---------------------------------------------------------------------------
#define DBM 128
#define DBN 160
#define DNKT 16
#define DEBLD 164

__global__ __launch_bounds__(256)
void decoder_mfma(const unsigned short* __restrict__ hd,
                  const unsigned short* __restrict__ w2tp,
                  const float* __restrict__ bd2,
                  float* __restrict__ recon)
{
    __shared__ __align__(16) char smem[40960];
    unsigned short* Alb = (unsigned short*)smem;            // [2][128*32]
    unsigned short* Blb = (unsigned short*)(smem + 16384);  // [2][192*32]
    float* eb = (float*)smem;

    const int tid = threadIdx.x;
    // XCD-aware swizzle: 1280 blocks = 8 XCDs x 32 m-tiles x 5 n-chunks
    const int bid = blockIdx.x;
    const int cxd = bid & 7;
    const int s = bid >> 3;
    const int m0 = (cxd * 32 + s / 5) * DBM;
    const int n0 = (s % 5) * DBN;

    const int wave = tid >> 6;
    const int wr = wave >> 1;
    const int wc = wave & 1;
    const int lane = tid & 63;
    const int lr = lane & 15;
    const int kg = lane >> 4;

    const int rS = tid >> 2;
    const int cS = (tid & 3) * 8;

    f32x4 acc[4][5];
    #pragma unroll
    for (int i = 0; i < 4; ++i)
        #pragma unroll
        for (int j = 0; j < 5; ++j)
            acc[i][j] = (f32x4){0.f, 0.f, 0.f, 0.f};

    #define DEC_STAGE(b, kt)                                                             \
    {                                                                                    \
        const int k0 = (kt) * 32 + cS;                                                   \
        gload16(&hd[(size_t)(m0 + rS) * HDIM + k0],          &Alb[(b) * 4096 + tid * 8]); \
        gload16(&hd[(size_t)(m0 + rS + 64) * HDIM + k0],     &Alb[(b) * 4096 + (tid + 256) * 8]); \
        gload16(&w2tp[(size_t)(n0 + rS) * HDIM + k0],        &Blb[(b) * 6144 + tid * 8]); \
        gload16(&w2tp[(size_t)(n0 + rS + 64) * HDIM + k0],   &Blb[(b) * 6144 + (tid + 256) * 8]); \
        gload16(&w2tp[(size_t)(n0 + rS + 128) * HDIM + k0],  &Blb[(b) * 6144 + (tid + 512) * 8]); \
    }

    DEC_STAGE(0, 0);

    int buf = 0;
    for (int kt = 0; kt < DNKT; ++kt) {
        if (kt + 1 < DNKT) {
            DEC_STAGE(buf ^ 1, kt + 1);
            asm volatile("s_waitcnt vmcnt(5)" ::: "memory");
        } else {
            asm volatile("s_waitcnt vmcnt(0)" ::: "memory");
        }
        __builtin_amdgcn_s_barrier();
        __builtin_amdgcn_sched_barrier(0);

        bf16x8 af[4], bfr[5];
        #pragma unroll
        for (int mi = 0; mi < 4; ++mi)
            af[mi] = *reinterpret_cast<const bf16x8*>(
                &Alb[buf * 4096 + (wr * 64 + mi * 16 + lr) * 32 + kg * 8]);
        #pragma unroll
        for (int nf = 0; nf < 5; ++nf)
            bfr[nf] = *reinterpret_cast<const bf16x8*>(
                &Blb[buf * 6144 + (wc * 80 + nf * 16 + lr) * 32 + kg * 8]);
        #pragma unroll
        for (int mi = 0; mi < 4; ++mi)
            #pragma unroll
            for (int nf = 0; nf < 5; ++nf)
                acc[mi][nf] = __builtin_amdgcn_mfma_f32_16x16x32_bf16(af[mi], bfr[nf], acc[mi][nf], 0, 0, 0);

        __builtin_amdgcn_sched_barrier(0);
        __builtin_amdgcn_s_barrier();
        buf ^= 1;
    }

    // ---- LDS-staged coalesced epilogue, nontemporal ext-vector stores
    #pragma unroll
    for (int mi = 0; mi < 4; ++mi) {
        __syncthreads();
        #pragma unroll
        for (int nf = 0; nf < 5; ++nf) {
            const int ci = wc * 80 + nf * 16 + lr;
            const int col = n0 + ci;
            const float bb = (col < XD) ? bd2[col] : 0.f;
            #pragma unroll
            for (int j = 0; j < 4; ++j) {
                const int ri = wr * 16 + kg * 4 + j;
                const float v = acc[mi][nf][j] + bb;
                eb[ri * DEBLD + ci] = __builtin_amdgcn_rcpf(1.f + __expf(-v));
            }
        }
        __syncthreads();
        #pragma unroll
        for (int e = 0; e < 5; ++e) {
            const int q = e * 256 + tid;
            const int ri = q / 40;
            const int c4 = (q - ri * 40) * 4;
            const int col = n0 + c4;
            if (col < XD) {
                const int grow = m0 + (ri >> 4) * 64 + mi * 16 + (ri & 15);
                const f32x4 v = *reinterpret_cast<const f32x4*>(&eb[ri * DEBLD + c4]);
                __builtin_nontemporal_store(
                    v, reinterpret_cast<f32x4*>(&recon[(size_t)grow * XD + col]));
            }
        }
    }
    #undef DEC_STAGE
}

// ---------------------------------------------------------------------------
extern "C" void kernel_launch(void* const* d_in, const int* in_sizes, int n_in,
                              void* d_out, int out_size, void* d_ws, size_t ws_size,
                              hipStream_t stream)
{
    const float* x    = (const float*)d_in[0];
    const float* eps  = (const float*)d_in[1];
    const float* W1   = (const float*)d_in[2];
    const float* b1   = (const float*)d_in[3];
    const float* Wmu  = (const float*)d_in[4];
    const float* bmu  = (const float*)d_in[5];
    const float* Wstd = (const float*)d_in[6];
    const float* bstd = (const float*)d_in[7];
    const float* Wd1  = (const float*)d_in[8];
    const float* bd1  = (const float*)d_in[9];
    const float* Wd2  = (const float*)d_in[10];
    const float* bd2  = (const float*)d_in[11];

    float* out    = (float*)d_out;
    float* recon  = out;
    float* mu     = recon + (size_t)NSAMP * XD;
    float* logvar = mu + (size_t)BATCH * ZS;
    float* zout   = logvar + (size_t)NSAMP * ZD;

    char* wsb = (char*)d_ws;
    unsigned short* hd   = (unsigned short*)wsb;                            // 32 MiB
    unsigned short* x_bf = (unsigned short*)wsb;                            // 6.25 MiB
    unsigned short* h    = (unsigned short*)(wsb + (size_t)68 * 1048576 / 10);
    float*          ms   = (float*)(wsb + (size_t)11 * 1048576);
    unsigned short* w1t  = (unsigned short*)(wsb + (size_t)295 * 1048576 / 10);
    unsigned short* wmst = (unsigned short*)(wsb + (size_t)305 * 1048576 / 10);
    unsigned short* w2tp = (unsigned short*)(wsb + (size_t)32 * 1048576);   // 832x512 bf16 reachable

    prep_kernel<<<7104, 256, 0, stream>>>(W1, x, Wmu, Wstd, Wd2, w1t, x_bf, wmst, w2tp);

    enc_mfma<1><<<dim3(BATCH / 128, HDIM / 128), 256, 0, stream>>>(
        x_bf, w1t, b1, b1, HDIM, h, HDIM, KP1);
    enc_mfma<0><<<dim3(BATCH / 128, NMS / 128), 256, 0, stream>>>(
        h, wmst, bmu, bstd, ZS, ms, NMS, HDIM);

    samphd_kernel<<<BATCH / 2, 256, 0, stream>>>(ms, eps, Wd1, bd1, mu, zout, logvar, hd);

    decoder_mfma<<<1280, 256, 0, stream>>>(hd, w2tp, bd2, recon);
}